// Round 4
// baseline (332.915 us; speedup 1.0000x reference)
//
#include <hip/hip_runtime.h>

// B=8, T=4096, C=1024, D=64 causal single-head attention. f32 in/out.
// 3 dispatches:
//   pack : one-time W repack f32 -> bf16 MFMA fragment layout
//          Wp[((wq*16+ks)*3+m)*2+k2][lane][8]. Wq pre-scaled by 0.125*log2e.
//   proj : ZERO-BARRIER GEMM. A-fragments loaded DIRECTLY from global X
//          (lane reads 32B contiguous; wave = 16 full 128B lines) -- no LDS,
//          no __syncthreads, so no vmcnt(0) drains anywhere. Rounds 1/3
//          showed the barrier drain costs ~10k cyc/k-step regardless of
//          occupancy (proj 67-70us at both 2 and 4 blocks/CU). Waves
//          free-run; half-k-step software pipeline; 4 waves/block share the
//          same X rows (redundant reads hit L1/L2). ~100 VGPR -> 4 w/SIMD.
//   flash: 1024 blocks = 8 batches x 128 q-tiles of 32 rows; 4 waves split
//          the KV range (split-softmax, merged via LDS). Fixed max=0.
//          K frags register-prefetched 1 KV-block ahead; V issued early.

typedef short bf16x8 __attribute__((ext_vector_type(8)));
typedef short bf16x4 __attribute__((ext_vector_type(4)));
typedef float f32x4  __attribute__((ext_vector_type(4)));

static __device__ __forceinline__ short f2bf(float x) {
    union { float f; unsigned u; } v; v.f = x;
    return (short)((v.u + 0x7fffu + ((v.u >> 16) & 1u)) >> 16);
}

// ---------------------------------------------------------------------------
// pack: grid 384, block 64. Block c packs one 1KB fragment chunk:
//   c = (wq*16 + ks)*6 + m*2 + k2
//   Wp[c*512 + lane*8 + j] = Wm[wq*16 + (lane&15)][ks*64 + k2*32 + (lane>>4)*8 + j]
// ---------------------------------------------------------------------------
__global__ __launch_bounds__(64) void pack_w_kernel(
    const float* __restrict__ Wk, const float* __restrict__ Wq,
    const float* __restrict__ Wv, short* __restrict__ Wp)
{
    const int c    = blockIdx.x;       // 0..383
    const int lane = threadIdx.x;      // 0..63
    const int k2   = c & 1;
    const int m    = (c >> 1) % 3;
    const int ksw  = c / 6;            // wq*16 + ks
    const int ks   = ksw & 15;
    const int wq   = ksw >> 4;
    const int l15  = lane & 15;
    const int quad = lane >> 4;
    const float* W = (m == 0) ? Wk : (m == 1) ? Wq : Wv;
    const float sc = (m == 1) ? 0.18033688f : 1.0f;   // 0.125*log2(e)
    const float* p = W + (long)(wq * 16 + l15) * 1024 + ks * 64 + k2 * 32 + quad * 8;
    f32x4 a = *(const f32x4*)(p);
    f32x4 b = *(const f32x4*)(p + 4);
    bf16x8 f;
#pragma unroll
    for (int j = 0; j < 4; ++j) { f[j] = f2bf(a[j] * sc); f[j + 4] = f2bf(b[j] * sc); }
    *(bf16x8*)(Wp + (long)c * 512 + lane * 8) = f;
}

// ---------------------------------------------------------------------------
// proj: grid 1024, block 256 (4 waves). Block = 32 rows x 192 out-cols.
// Wave w: out-cols w*16..w*16+15 of EACH of {K,Q,V}; rows all 32 (2 tiles).
// NO LDS / NO BARRIERS. 32 half-steps (ks,k2); X raw + W frags prefetched
// one half-step ahead; compiler free to hoist further (no sync fences).
// ---------------------------------------------------------------------------
__global__ __launch_bounds__(256, 4) void proj_kernel(
    const float* __restrict__ X,
    const short* __restrict__ Wp,
    short* __restrict__ Kb,   // [B*T,64] bf16
    short* __restrict__ Qb,   // [B*T,64] bf16 (exp2-domain scale folded)
    short* __restrict__ Vt)   // [B][64][4096] bf16
{
    const int tid  = threadIdx.x;
    const int w    = tid >> 6;
    const int lane = tid & 63;
    const int l15  = lane & 15;
    const int quad = lane >> 4;
    const int t0   = blockIdx.x * 32;

    // A-frag source rows (direct global): rt=0 -> row t0+l15, rt=1 -> +16
    const float* x0 = X + (long)(t0 + l15) * 1024 + quad * 8;
    const float* x1 = x0 + 16 * 1024;
    // packed W base for this wave; chunk (ks*6 + m*2 + k2), 512 shorts each
    const short* wp = Wp + (long)(w * 16) * 6 * 512 + lane * 8;

    f32x4 acc[2][3];
#pragma unroll
    for (int rt = 0; rt < 2; ++rt)
#pragma unroll
        for (int m = 0; m < 3; ++m) { acc[rt][m][0]=0.f; acc[rt][m][1]=0.f; acc[rt][m][2]=0.f; acc[rt][m][3]=0.f; }

    // pipeline state: raw X (16 f32) + W frags (3 m) for the CURRENT half-step
    f32x4 xa, xb, xc, xd;
    bf16x8 wc0, wc1, wc2;
    {
        xa = *(const f32x4*)(x0);     xb = *(const f32x4*)(x0 + 4);
        xc = *(const f32x4*)(x1);     xd = *(const f32x4*)(x1 + 4);
        wc0 = *(const bf16x8*)(wp);
        wc1 = *(const bf16x8*)(wp + 2 * 512);
        wc2 = *(const bf16x8*)(wp + 4 * 512);
    }

#pragma unroll
    for (int hs = 0; hs < 32; ++hs) {
        // prefetch next half-step (X from HBM/L2, W from L2)
        f32x4 na, nb, nc, nd;
        bf16x8 wn0, wn1, wn2;
        if (hs < 31) {
            const int nks = (hs + 1) >> 1, nk2 = (hs + 1) & 1;
            const int off = nks * 64 + nk2 * 32;
            na = *(const f32x4*)(x0 + off);  nb = *(const f32x4*)(x0 + off + 4);
            nc = *(const f32x4*)(x1 + off);  nd = *(const f32x4*)(x1 + off + 4);
            const short* wb = wp + (size_t)(nks * 6 + nk2) * 512;
            wn0 = *(const bf16x8*)(wb);
            wn1 = *(const bf16x8*)(wb + 2 * 512);
            wn2 = *(const bf16x8*)(wb + 4 * 512);
        }
        // convert current raw X -> A-frags
        bf16x8 a0, a1;
#pragma unroll
        for (int j = 0; j < 4; ++j) {
            a0[j] = f2bf(xa[j]); a0[j + 4] = f2bf(xb[j]);
            a1[j] = f2bf(xc[j]); a1[j + 4] = f2bf(xd[j]);
        }
        // 6 MFMAs (2 row-tiles x 3 outputs)
        acc[0][0] = __builtin_amdgcn_mfma_f32_16x16x32_bf16(a0, wc0, acc[0][0], 0, 0, 0);
        acc[1][0] = __builtin_amdgcn_mfma_f32_16x16x32_bf16(a1, wc0, acc[1][0], 0, 0, 0);
        acc[0][1] = __builtin_amdgcn_mfma_f32_16x16x32_bf16(a0, wc1, acc[0][1], 0, 0, 0);
        acc[1][1] = __builtin_amdgcn_mfma_f32_16x16x32_bf16(a1, wc1, acc[1][1], 0, 0, 0);
        acc[0][2] = __builtin_amdgcn_mfma_f32_16x16x32_bf16(a0, wc2, acc[0][2], 0, 0, 0);
        acc[1][2] = __builtin_amdgcn_mfma_f32_16x16x32_bf16(a1, wc2, acc[1][2], 0, 0, 0);
        // rotate pipeline (full unroll -> pure SSA renaming, no moves)
        xa = na; xb = nb; xc = nc; xd = nd;
        wc0 = wn0; wc1 = wn1; wc2 = wn2;
    }

    // epilogue: C layout row = quad*4+r, col = l15; out-col d = w*16+l15
    const int d    = w * 16 + l15;
    const int bidx = t0 >> 12;
#pragma unroll
    for (int rt = 0; rt < 2; ++rt) {
        const int tf = t0 + rt * 16 + quad * 4;
#pragma unroll
        for (int r = 0; r < 4; ++r) Kb[(long)(tf + r) * 64 + d] = f2bf(acc[rt][0][r]);
#pragma unroll
        for (int r = 0; r < 4; ++r) Qb[(long)(tf + r) * 64 + d] = f2bf(acc[rt][1][r]);
        bf16x4 pv;
#pragma unroll
        for (int r = 0; r < 4; ++r) pv[r] = f2bf(acc[rt][2][r]);
        *(bf16x4*)(Vt + ((long)bidx * 64 + d) * 4096 + (tf & 4095)) = pv;
    }
}

// ---------------------------------------------------------------------------
// flash: grid 1024 = 8 batches x 128 tiles of 32 q-rows. 4 waves split KV.
// ---------------------------------------------------------------------------
__global__ __launch_bounds__(256, 2) void flash_kernel(
    const short* __restrict__ Qb,
    const short* __restrict__ Kb,
    const short* __restrict__ Vt,
    float* __restrict__ Out)
{
    __shared__ __align__(16) char smem[33280];
    short* ps = (short*)smem;             // loop : [w][qt2][16][72] bf16
    float* os = (float*)smem;             // merge: [w][32][64] f32
    float* ls = (float*)(smem + 32768);   // merge: [w][32]

    const int tid  = threadIdx.x;
    const int w    = tid >> 6;
    const int lane = tid & 63;
    const int l15  = lane & 15;
    const int quad = lane >> 4;
    const int b    = blockIdx.x & 7;             // XCD-local batch (%8 swizzle)
    const int tile = 127 - (blockIdx.x >> 3);    // heavy tiles first
    const int t0   = tile * 32;

    const int nkb = (t0 >> 6) + 1;
    const int len = (nkb + 3) >> 2;
    const int kb0 = w * len;
    const int kb1 = (kb0 + len < nkb) ? (kb0 + len) : nkb;

    const short* Kbase = Kb + (long)b * 4096 * 64;
    const short* Vbase = Vt + (long)b * 64 * 4096;

    bf16x8 aq[2][2];
#pragma unroll
    for (int q2 = 0; q2 < 2; ++q2) {
        const long qoff = ((long)b * 4096 + t0 + q2 * 16 + l15) * 64;
        aq[q2][0] = *(const bf16x8*)(Qb + qoff + quad * 8);
        aq[q2][1] = *(const bf16x8*)(Qb + qoff + 32 + quad * 8);
    }

    bf16x8 bones;   // ones-column B-frag for row-sums
#pragma unroll
    for (int j = 0; j < 8; ++j) bones[j] = (l15 == 0) ? (short)0x3F80 : (short)0;

    f32x4 o[2][4], lacc[2];
#pragma unroll
    for (int q2 = 0; q2 < 2; ++q2) {
        lacc[q2][0]=0.f; lacc[q2][1]=0.f; lacc[q2][2]=0.f; lacc[q2][3]=0.f;
#pragma unroll
        for (int dt = 0; dt < 4; ++dt) { o[q2][dt][0]=0.f; o[q2][dt][1]=0.f; o[q2][dt][2]=0.f; o[q2][dt][3]=0.f; }
    }

    bf16x8 kc[4][2], kn[4][2];
    if (kb0 < kb1) {
        const int s0 = kb0 << 6;
#pragma unroll
        for (int ct = 0; ct < 4; ++ct) {
            const short* kp = Kbase + (long)(s0 + ct * 16 + l15) * 64 + quad * 8;
            kc[ct][0] = *(const bf16x8*)(kp);
            kc[ct][1] = *(const bf16x8*)(kp + 32);
        }
    }

    for (int kb = kb0; kb < kb1; ++kb) {
        const int s0 = kb << 6;

        // V frags early (consumed at iteration end)
        bf16x8 vf[4][2];
#pragma unroll
        for (int dt = 0; dt < 4; ++dt) {
            const short* vp = Vbase + (long)(dt * 16 + l15) * 4096 + s0 + quad * 8;
            vf[dt][0] = *(const bf16x8*)(vp);
            vf[dt][1] = *(const bf16x8*)(vp + 32);
        }
        // K prefetch for next iter
        if (kb + 1 < kb1) {
            const int sn = s0 + 64;
#pragma unroll
            for (int ct = 0; ct < 4; ++ct) {
                const short* kp = Kbase + (long)(sn + ct * 16 + l15) * 64 + quad * 8;
                kn[ct][0] = *(const bf16x8*)(kp);
                kn[ct][1] = *(const bf16x8*)(kp + 32);
            }
        }

#pragma unroll
        for (int q2 = 0; q2 < 2; ++q2) {
            short* myps = ps + ((w << 1) | q2) * 1152;
            // S (exp2-domain)
            f32x4 st[4];
#pragma unroll
            for (int ct = 0; ct < 4; ++ct) {
                f32x4 z; z[0]=0.f; z[1]=0.f; z[2]=0.f; z[3]=0.f;
                z = __builtin_amdgcn_mfma_f32_16x16x32_bf16(aq[q2][0], kc[ct][0], z, 0, 0, 0);
                st[ct] = __builtin_amdgcn_mfma_f32_16x16x32_bf16(aq[q2][1], kc[ct][1], st[ct] = z, 0, 0, 0);
            }
            if (kb == nkb - 1) {   // diagonal: mask s > q
#pragma unroll
                for (int ct = 0; ct < 4; ++ct) {
                    const int s = s0 + ct * 16 + l15;
#pragma unroll
                    for (int r = 0; r < 4; ++r)
                        if (s > t0 + q2 * 16 + quad * 4 + r) st[ct][r] = -1e30f;
                }
            }
            // P = exp2(S) -> bf16 LDS (C-layout)
#pragma unroll
            for (int ct = 0; ct < 4; ++ct)
#pragma unroll
                for (int r = 0; r < 4; ++r)
                    myps[(quad * 4 + r) * 72 + ct * 16 + l15] =
                        f2bf(__builtin_amdgcn_exp2f(st[ct][r]));
            // P A-frags
            bf16x8 ap0 = *(const bf16x8*)(myps + l15 * 72 + quad * 8);
            bf16x8 ap1 = *(const bf16x8*)(myps + l15 * 72 + 32 + quad * 8);
            // row-sums + O += P V
            lacc[q2] = __builtin_amdgcn_mfma_f32_16x16x32_bf16(ap0, bones, lacc[q2], 0, 0, 0);
            lacc[q2] = __builtin_amdgcn_mfma_f32_16x16x32_bf16(ap1, bones, lacc[q2], 0, 0, 0);
#pragma unroll
            for (int dt = 0; dt < 4; ++dt) {
                o[q2][dt] = __builtin_amdgcn_mfma_f32_16x16x32_bf16(ap0, vf[dt][0], o[q2][dt], 0, 0, 0);
                o[q2][dt] = __builtin_amdgcn_mfma_f32_16x16x32_bf16(ap1, vf[dt][1], o[q2][dt], 0, 0, 0);
            }
        }
#pragma unroll
        for (int ct = 0; ct < 4; ++ct) { kc[ct][0] = kn[ct][0]; kc[ct][1] = kn[ct][1]; }
    }

    // merge the 4 waves' partials (shared exp base -> pure sums)
    __syncthreads();
#pragma unroll
    for (int q2 = 0; q2 < 2; ++q2) {
#pragma unroll
        for (int dt = 0; dt < 4; ++dt)
#pragma unroll
            for (int r = 0; r < 4; ++r)
                os[w * 2048 + (q2 * 16 + quad * 4 + r) * 64 + dt * 16 + l15] = o[q2][dt][r];
        if (l15 == 0) {
#pragma unroll
            for (int r = 0; r < 4; ++r) ls[w * 32 + q2 * 16 + quad * 4 + r] = lacc[q2][r];
        }
    }
    __syncthreads();

    const int row = tid >> 3, c0 = (tid & 7) * 8;
    f32x4 a0, a1; a0[0]=0.f;a0[1]=0.f;a0[2]=0.f;a0[3]=0.f; a1=a0;
    float lsum = 0.f;
#pragma unroll
    for (int w2 = 0; w2 < 4; ++w2) {
        f32x4 v0 = *(const f32x4*)(os + w2 * 2048 + row * 64 + c0);
        f32x4 v1 = *(const f32x4*)(os + w2 * 2048 + row * 64 + c0 + 4);
        a0[0]+=v0[0]; a0[1]+=v0[1]; a0[2]+=v0[2]; a0[3]+=v0[3];
        a1[0]+=v1[0]; a1[1]+=v1[1]; a1[2]+=v1[2]; a1[3]+=v1[3];
        lsum += ls[w2 * 32 + row];
    }
    const float inv = 1.0f / lsum;
    f32x4 r0, r1;
    r0[0]=a0[0]*inv; r0[1]=a0[1]*inv; r0[2]=a0[2]*inv; r0[3]=a0[3]*inv;
    r1[0]=a1[0]*inv; r1[1]=a1[1]*inv; r1[2]=a1[2]*inv; r1[3]=a1[3]*inv;
    float* op = Out + ((long)b * 4096 + t0 + row) * 64 + c0;
    *(f32x4*)(op)     = r0;
    *(f32x4*)(op + 4) = r1;
}

// ---------------------------------------------------------------------------
extern "C" void kernel_launch(void* const* d_in, const int* in_sizes, int n_in,
                              void* d_out, int out_size, void* d_ws, size_t ws_size,
                              hipStream_t stream) {
    const float* X  = (const float*)d_in[0];
    const float* Wk = (const float*)d_in[1];
    const float* Wq = (const float*)d_in[2];
    const float* Wv = (const float*)d_in[3];

    short* ws = (short*)d_ws;
    const long NE = (long)8 * 4096 * 64;
    short* Qb = ws;
    short* Kb = ws + NE;
    short* Vt = ws + 2 * NE;        // 12 MB
    short* Wpk = ws + 3 * NE;       // +384 KB packed W fragments

    pack_w_kernel<<<384, 64, 0, stream>>>(Wk, Wq, Wv, Wpk);
    proj_kernel<<<1024, 256, 0, stream>>>(X, Wpk, Kb, Qb, Vt);
    flash_kernel<<<1024, 256, 0, stream>>>(Qb, Kb, Vt, (float*)d_out);
}

// Round 5
// 273.649 us; speedup vs baseline: 1.2166x; 1.2166x over previous
//
#include <hip/hip_runtime.h>

// B=8, T=4096, C=1024, D=64 causal single-head attention. f32 in/out.
// 3 dispatches:
//   pack : one-time W repack f32 -> bf16 MFMA fragment layout
//          Wp[((wq*16+ks)*3+m)*2+k2][lane][8]. Wq pre-scaled by 0.125*log2e.
//   proj : ROUND-1 VERSION (measured 67us; best of 5 attempts). 64-row
//          blocks, grid 512, LDS X dbuf, 2-deep X prefetch, packed-W
//          register prefetch, 1 barrier/k-step. (Round-2 K-split: 198us.
//          Round-3 32-row/4blk: 70us. Round-4 barrier-free direct-global:
//          120us, 674GB/s - DRAM page thrash + compiler JIT-load at 32 VGPR.)
//   flash: 1024 blocks = 8 batches x 128 q-tiles of 32 rows; 4 waves split
//          the KV range (split-softmax, merged via LDS). Fixed max=0.
//          THIS ROUND: the two q2 sub-tiles' chains are phase-FUSED
//          (QK both -> exp2/cvt/store both -> one lgkm wait -> PV both)
//          to double ILP at every latency point at ~2 waves/SIMD.
//          K frags register-prefetched 1 KV-block ahead; V issued early.

typedef short bf16x8 __attribute__((ext_vector_type(8)));
typedef short bf16x4 __attribute__((ext_vector_type(4)));
typedef float f32x4  __attribute__((ext_vector_type(4)));

static __device__ __forceinline__ short f2bf(float x) {
    union { float f; unsigned u; } v; v.f = x;
    return (short)((v.u + 0x7fffu + ((v.u >> 16) & 1u)) >> 16);
}

// ---------------------------------------------------------------------------
// pack: grid 384, block 64. Block c packs one 1KB fragment chunk:
//   c = (wq*16 + ks)*6 + m*2 + k2
//   Wp[c*512 + lane*8 + j] = Wm[wq*16 + (lane&15)][ks*64 + k2*32 + (lane>>4)*8 + j]
// ---------------------------------------------------------------------------
__global__ __launch_bounds__(64) void pack_w_kernel(
    const float* __restrict__ Wk, const float* __restrict__ Wq,
    const float* __restrict__ Wv, short* __restrict__ Wp)
{
    const int c    = blockIdx.x;       // 0..383
    const int lane = threadIdx.x;      // 0..63
    const int k2   = c & 1;
    const int m    = (c >> 1) % 3;
    const int ksw  = c / 6;            // wq*16 + ks
    const int ks   = ksw & 15;
    const int wq   = ksw >> 4;
    const int l15  = lane & 15;
    const int quad = lane >> 4;
    const float* W = (m == 0) ? Wk : (m == 1) ? Wq : Wv;
    const float sc = (m == 1) ? 0.18033688f : 1.0f;   // 0.125*log2(e)
    const float* p = W + (long)(wq * 16 + l15) * 1024 + ks * 64 + k2 * 32 + quad * 8;
    f32x4 a = *(const f32x4*)(p);
    f32x4 b = *(const f32x4*)(p + 4);
    bf16x8 f;
#pragma unroll
    for (int j = 0; j < 4; ++j) { f[j] = f2bf(a[j] * sc); f[j + 4] = f2bf(b[j] * sc); }
    *(bf16x8*)(Wp + (long)c * 512 + lane * 8) = f;
}

// ---------------------------------------------------------------------------
// proj: grid 512, block 256 (4 waves). Block = 64 rows x 192 out-cols.
// Wave w: out-cols w*16..w*16+15 of EACH of {K,Q,V}; rows all 64 (4 tiles).
// W fragments come pre-packed from Wp: 6 coalesced bf16x8 loads/iter/thread.
// ---------------------------------------------------------------------------
__global__ __launch_bounds__(256, 2) void proj_kernel(
    const float* __restrict__ X,
    const short* __restrict__ Wp,
    short* __restrict__ Kb,   // [B*T,64] bf16
    short* __restrict__ Qb,   // [B*T,64] bf16 (exp2-domain scale folded)
    short* __restrict__ Vt)   // [B][64][4096] bf16
{
    __shared__ __align__(16) short xs[2][64 * 72];   // 64 rows, stride 72
    const int tid  = threadIdx.x;
    const int w    = tid >> 6;
    const int lane = tid & 63;
    const int l15  = lane & 15;
    const int quad = lane >> 4;
    const int t0   = blockIdx.x * 64;

    // --- X staging addresses: 2 chunks/thread, 8 f32 each -> 1 b128 LDS write
    const int rowA = tid >> 3, colg = tid & 7;
    const int rowB = rowA + 32;
    const float* xpA = X + (long)(t0 + rowA) * 1024 + colg * 8;
    const float* xpB = X + (long)(t0 + rowB) * 1024 + colg * 8;
    const int lwA = rowA * 72 + colg * 8;
    const int lwB = rowB * 72 + colg * 8;

    // --- packed W base for this wave (chunks are 512 shorts = 1KB each)
    const short* wp = Wp + (long)(w * 16) * 6 * 512 + lane * 8;

    f32x4 acc[4][3];
#pragma unroll
    for (int rt = 0; rt < 4; ++rt)
#pragma unroll
        for (int m = 0; m < 3; ++m) { acc[rt][m][0]=0.f; acc[rt][m][1]=0.f; acc[rt][m][2]=0.f; acc[rt][m][3]=0.f; }

    f32x4 xr[2][4];        // 2 prefetch sets x (2 chunks x 2 halves)
    bf16x8 wfc[3][2], wfn[3][2];

    // prologue: X for ks=0,1; W chunks for ks=0
    {
#pragma unroll
        for (int s = 0; s < 2; ++s) {
            const int k0 = s * 64;
            xr[s][0] = *(const f32x4*)(xpA + k0);
            xr[s][1] = *(const f32x4*)(xpA + k0 + 4);
            xr[s][2] = *(const f32x4*)(xpB + k0);
            xr[s][3] = *(const f32x4*)(xpB + k0 + 4);
        }
#pragma unroll
        for (int m = 0; m < 3; ++m)
#pragma unroll
            for (int k2 = 0; k2 < 2; ++k2)
                wfc[m][k2] = *(const bf16x8*)(wp + (m * 2 + k2) * 512);
        // flush set0 (ks=0) into buf0
        bf16x8 c0, c1;
#pragma unroll
        for (int j = 0; j < 4; ++j) { c0[j] = f2bf(xr[0][0][j]); c0[j+4] = f2bf(xr[0][1][j]);
                                      c1[j] = f2bf(xr[0][2][j]); c1[j+4] = f2bf(xr[0][3][j]); }
        *(bf16x8*)(&xs[0][lwA]) = c0;
        *(bf16x8*)(&xs[0][lwB]) = c1;
    }
    __syncthreads();

#pragma unroll 2
    for (int ks = 0; ks < 16; ++ks) {
        const int buf = ks & 1;
        // X prefetch 2 ahead into the just-flushed set
        if (ks < 14) {
            const int k0 = (ks + 2) * 64;
            xr[buf][0] = *(const f32x4*)(xpA + k0);
            xr[buf][1] = *(const f32x4*)(xpA + k0 + 4);
            xr[buf][2] = *(const f32x4*)(xpB + k0);
            xr[buf][3] = *(const f32x4*)(xpB + k0 + 4);
        }
        // packed-W loads 1 ahead (L2-resident, coalesced 1KB/wave each)
        if (ks < 15) {
            const int cb = (ks + 1) * 6;
#pragma unroll
            for (int m = 0; m < 3; ++m)
#pragma unroll
                for (int k2 = 0; k2 < 2; ++k2)
                    wfn[m][k2] = *(const bf16x8*)(wp + (cb + m * 2 + k2) * 512);
        }
        // compute on buf
#pragma unroll
        for (int k2 = 0; k2 < 2; ++k2)
#pragma unroll
            for (int rt = 0; rt < 4; ++rt) {
                bf16x8 a = *(const bf16x8*)(&xs[buf][(rt * 16 + l15) * 72 + k2 * 32 + quad * 8]);
#pragma unroll
                for (int m = 0; m < 3; ++m)
                    acc[rt][m] = __builtin_amdgcn_mfma_f32_16x16x32_bf16(a, wfc[m][k2], acc[rt][m], 0, 0, 0);
            }
        if (ks < 15) {
            // flush X set for ks+1 into other buffer
            const int nset = (ks + 1) & 1;
            bf16x8 c0, c1;
#pragma unroll
            for (int j = 0; j < 4; ++j) { c0[j] = f2bf(xr[nset][0][j]); c0[j+4] = f2bf(xr[nset][1][j]);
                                          c1[j] = f2bf(xr[nset][2][j]); c1[j+4] = f2bf(xr[nset][3][j]); }
            *(bf16x8*)(&xs[nset][lwA]) = c0;
            *(bf16x8*)(&xs[nset][lwB]) = c1;
        }
        __syncthreads();
#pragma unroll
        for (int m = 0; m < 3; ++m)
#pragma unroll
            for (int k2 = 0; k2 < 2; ++k2) wfc[m][k2] = wfn[m][k2];
    }

    // epilogue: C layout row = quad*4+r, col = l15; out-col d = w*16+l15
    const int d    = w * 16 + l15;
    const int bidx = t0 >> 12;
#pragma unroll
    for (int rt = 0; rt < 4; ++rt) {
        const int tf = t0 + rt * 16 + quad * 4;
#pragma unroll
        for (int r = 0; r < 4; ++r) Kb[(long)(tf + r) * 64 + d] = f2bf(acc[rt][0][r]);
#pragma unroll
        for (int r = 0; r < 4; ++r) Qb[(long)(tf + r) * 64 + d] = f2bf(acc[rt][1][r]);
        bf16x4 pv;
#pragma unroll
        for (int r = 0; r < 4; ++r) pv[r] = f2bf(acc[rt][2][r]);
        *(bf16x4*)(Vt + ((long)bidx * 64 + d) * 4096 + (tf & 4095)) = pv;
    }
}

// ---------------------------------------------------------------------------
// flash: grid 1024 = 8 batches x 128 tiles of 32 q-rows. 4 waves split KV.
// q2-FUSED inner loop: both q-sub-tiles advance phase-by-phase so every
// latency point (QK chain, exp2/cvt, LDS wait, PV chain) has 2 independent
// streams in flight. One lgkmcnt wait per kb instead of two.
// ---------------------------------------------------------------------------
__global__ __launch_bounds__(256, 2) void flash_kernel(
    const short* __restrict__ Qb,
    const short* __restrict__ Kb,
    const short* __restrict__ Vt,
    float* __restrict__ Out)
{
    __shared__ __align__(16) char smem[33280];
    short* ps = (short*)smem;             // loop : [w][qt2][16][72] bf16
    float* os = (float*)smem;             // merge: [w][32][64] f32
    float* ls = (float*)(smem + 32768);   // merge: [w][32]

    const int tid  = threadIdx.x;
    const int w    = tid >> 6;
    const int lane = tid & 63;
    const int l15  = lane & 15;
    const int quad = lane >> 4;
    const int b    = blockIdx.x & 7;             // XCD-local batch (%8 swizzle)
    const int tile = 127 - (blockIdx.x >> 3);    // heavy tiles first
    const int t0   = tile * 32;

    const int nkb = (t0 >> 6) + 1;
    const int len = (nkb + 3) >> 2;
    const int kb0 = w * len;
    const int kb1 = (kb0 + len < nkb) ? (kb0 + len) : nkb;

    const short* Kbase = Kb + (long)b * 4096 * 64;
    const short* Vbase = Vt + (long)b * 64 * 4096;

    bf16x8 aq[2][2];
#pragma unroll
    for (int q2 = 0; q2 < 2; ++q2) {
        const long qoff = ((long)b * 4096 + t0 + q2 * 16 + l15) * 64;
        aq[q2][0] = *(const bf16x8*)(Qb + qoff + quad * 8);
        aq[q2][1] = *(const bf16x8*)(Qb + qoff + 32 + quad * 8);
    }

    bf16x8 bones;   // ones-column B-frag for row-sums
#pragma unroll
    for (int j = 0; j < 8; ++j) bones[j] = (l15 == 0) ? (short)0x3F80 : (short)0;

    f32x4 o[2][4], lacc[2];
#pragma unroll
    for (int q2 = 0; q2 < 2; ++q2) {
        lacc[q2][0]=0.f; lacc[q2][1]=0.f; lacc[q2][2]=0.f; lacc[q2][3]=0.f;
#pragma unroll
        for (int dt = 0; dt < 4; ++dt) { o[q2][dt][0]=0.f; o[q2][dt][1]=0.f; o[q2][dt][2]=0.f; o[q2][dt][3]=0.f; }
    }

    bf16x8 kc[4][2], kn[4][2];
    if (kb0 < kb1) {
        const int s0 = kb0 << 6;
#pragma unroll
        for (int ct = 0; ct < 4; ++ct) {
            const short* kp = Kbase + (long)(s0 + ct * 16 + l15) * 64 + quad * 8;
            kc[ct][0] = *(const bf16x8*)(kp);
            kc[ct][1] = *(const bf16x8*)(kp + 32);
        }
    }

    short* myps0 = ps + ((w << 1) | 0) * 1152;
    short* myps1 = ps + ((w << 1) | 1) * 1152;

    for (int kb = kb0; kb < kb1; ++kb) {
        const int s0 = kb << 6;

        // V frags early (consumed at iteration end)
        bf16x8 vf[4][2];
#pragma unroll
        for (int dt = 0; dt < 4; ++dt) {
            const short* vp = Vbase + (long)(dt * 16 + l15) * 4096 + s0 + quad * 8;
            vf[dt][0] = *(const bf16x8*)(vp);
            vf[dt][1] = *(const bf16x8*)(vp + 32);
        }
        // K prefetch for next iter
        if (kb + 1 < kb1) {
            const int sn = s0 + 64;
#pragma unroll
            for (int ct = 0; ct < 4; ++ct) {
                const short* kp = Kbase + (long)(sn + ct * 16 + l15) * 64 + quad * 8;
                kn[ct][0] = *(const bf16x8*)(kp);
                kn[ct][1] = *(const bf16x8*)(kp + 32);
            }
        }

        // ---- phase 1: QK^T for BOTH q2 (16 dense MFMAs, 2 indep chains)
        f32x4 st[2][4];
#pragma unroll
        for (int q2 = 0; q2 < 2; ++q2)
#pragma unroll
            for (int ct = 0; ct < 4; ++ct) {
                f32x4 z; z[0]=0.f; z[1]=0.f; z[2]=0.f; z[3]=0.f;
                z = __builtin_amdgcn_mfma_f32_16x16x32_bf16(aq[q2][0], kc[ct][0], z, 0, 0, 0);
                st[q2][ct] = __builtin_amdgcn_mfma_f32_16x16x32_bf16(aq[q2][1], kc[ct][1], z, 0, 0, 0);
            }
        // ---- phase 2: diagonal mask (last kb only)
        if (kb == nkb - 1) {
#pragma unroll
            for (int q2 = 0; q2 < 2; ++q2)
#pragma unroll
                for (int ct = 0; ct < 4; ++ct) {
                    const int s = s0 + ct * 16 + l15;
#pragma unroll
                    for (int r = 0; r < 4; ++r)
                        if (s > t0 + q2 * 16 + quad * 4 + r) st[q2][ct][r] = -1e30f;
                }
        }
        // ---- phase 3: P = exp2(S) -> bf16 LDS for BOTH q2
#pragma unroll
        for (int ct = 0; ct < 4; ++ct)
#pragma unroll
            for (int r = 0; r < 4; ++r) {
                myps0[(quad * 4 + r) * 72 + ct * 16 + l15] =
                    f2bf(__builtin_amdgcn_exp2f(st[0][ct][r]));
                myps1[(quad * 4 + r) * 72 + ct * 16 + l15] =
                    f2bf(__builtin_amdgcn_exp2f(st[1][ct][r]));
            }
        // ---- phase 4: P A-frags for BOTH q2 (single LDS wait covers all)
        bf16x8 ap[2][2];
        ap[0][0] = *(const bf16x8*)(myps0 + l15 * 72 + quad * 8);
        ap[0][1] = *(const bf16x8*)(myps0 + l15 * 72 + 32 + quad * 8);
        ap[1][0] = *(const bf16x8*)(myps1 + l15 * 72 + quad * 8);
        ap[1][1] = *(const bf16x8*)(myps1 + l15 * 72 + 32 + quad * 8);
        // ---- phase 5: row-sums + O += P V for BOTH q2 (20 dense MFMAs)
#pragma unroll
        for (int q2 = 0; q2 < 2; ++q2) {
            lacc[q2] = __builtin_amdgcn_mfma_f32_16x16x32_bf16(ap[q2][0], bones, lacc[q2], 0, 0, 0);
            lacc[q2] = __builtin_amdgcn_mfma_f32_16x16x32_bf16(ap[q2][1], bones, lacc[q2], 0, 0, 0);
        }
#pragma unroll
        for (int q2 = 0; q2 < 2; ++q2)
#pragma unroll
            for (int dt = 0; dt < 4; ++dt) {
                o[q2][dt] = __builtin_amdgcn_mfma_f32_16x16x32_bf16(ap[q2][0], vf[dt][0], o[q2][dt], 0, 0, 0);
                o[q2][dt] = __builtin_amdgcn_mfma_f32_16x16x32_bf16(ap[q2][1], vf[dt][1], o[q2][dt], 0, 0, 0);
            }
#pragma unroll
        for (int ct = 0; ct < 4; ++ct) { kc[ct][0] = kn[ct][0]; kc[ct][1] = kn[ct][1]; }
    }

    // merge the 4 waves' partials (shared exp base -> pure sums)
    __syncthreads();
#pragma unroll
    for (int q2 = 0; q2 < 2; ++q2) {
#pragma unroll
        for (int dt = 0; dt < 4; ++dt)
#pragma unroll
            for (int r = 0; r < 4; ++r)
                os[w * 2048 + (q2 * 16 + quad * 4 + r) * 64 + dt * 16 + l15] = o[q2][dt][r];
        if (l15 == 0) {
#pragma unroll
            for (int r = 0; r < 4; ++r) ls[w * 32 + q2 * 16 + quad * 4 + r] = lacc[q2][r];
        }
    }
    __syncthreads();

    const int row = tid >> 3, c0 = (tid & 7) * 8;
    f32x4 a0, a1; a0[0]=0.f;a0[1]=0.f;a0[2]=0.f;a0[3]=0.f; a1=a0;
    float lsum = 0.f;
#pragma unroll
    for (int w2 = 0; w2 < 4; ++w2) {
        f32x4 v0 = *(const f32x4*)(os + w2 * 2048 + row * 64 + c0);
        f32x4 v1 = *(const f32x4*)(os + w2 * 2048 + row * 64 + c0 + 4);
        a0[0]+=v0[0]; a0[1]+=v0[1]; a0[2]+=v0[2]; a0[3]+=v0[3];
        a1[0]+=v1[0]; a1[1]+=v1[1]; a1[2]+=v1[2]; a1[3]+=v1[3];
        lsum += ls[w2 * 32 + row];
    }
    const float inv = 1.0f / lsum;
    f32x4 r0, r1;
    r0[0]=a0[0]*inv; r0[1]=a0[1]*inv; r0[2]=a0[2]*inv; r0[3]=a0[3]*inv;
    r1[0]=a1[0]*inv; r1[1]=a1[1]*inv; r1[2]=a1[2]*inv; r1[3]=a1[3]*inv;
    float* op = Out + ((long)b * 4096 + t0 + row) * 64 + c0;
    *(f32x4*)(op)     = r0;
    *(f32x4*)(op + 4) = r1;
}

// ---------------------------------------------------------------------------
extern "C" void kernel_launch(void* const* d_in, const int* in_sizes, int n_in,
                              void* d_out, int out_size, void* d_ws, size_t ws_size,
                              hipStream_t stream) {
    const float* X  = (const float*)d_in[0];
    const float* Wk = (const float*)d_in[1];
    const float* Wq = (const float*)d_in[2];
    const float* Wv = (const float*)d_in[3];

    short* ws = (short*)d_ws;
    const long NE = (long)8 * 4096 * 64;
    short* Qb = ws;
    short* Kb = ws + NE;
    short* Vt = ws + 2 * NE;        // 12 MB
    short* Wpk = ws + 3 * NE;       // +384 KB packed W fragments

    pack_w_kernel<<<384, 64, 0, stream>>>(Wk, Wq, Wv, Wpk);
    proj_kernel<<<512, 256, 0, stream>>>(X, Wpk, Kb, Qb, Vt);
    flash_kernel<<<1024, 256, 0, stream>>>(Qb, Kb, Vt, (float*)d_out);
}